// Round 6
// baseline (99.990 us; speedup 1.0000x reference)
//
#include <hip/hip_runtime.h>

// Problem constants (fixed by the reference):
//   z: (1, 512, 32, 32) fp32   -> C=512 channels, P=1024 template positions
//   x: (3, 512, 256, 256) fp32 -> B=3, N=65536 pixels
// res[b,n] = 0.001 * sum_c ( sum_p z[c,p] ) * x[b,c,n]
constexpr int C    = 512;
constexpr int P    = 1024;     // 32*32
constexpr int NPIX = 65536;    // 256*256
constexpr int B    = 3;
constexpr int NF4  = B * NPIX / 4;    // 49152 float4 outputs

// Native clang vector type: __builtin_nontemporal_load/store accept this
// (HIP_vector_type float4 is a struct -> rejected).
typedef float f32x4 __attribute__((ext_vector_type(4)));

// ---------------------------------------------------------------------------
// Kernel 1: zsum[c] = sum over P of z[c,p]. One single-wave block per channel
// (512 blocks = 2/CU even spread). Lane l reads 4 float4s -> coalesced 1 KB
// per wave per step. z is read-once -> non-temporal.
// ---------------------------------------------------------------------------
__global__ __launch_bounds__(64) void zsum_kernel(const float* __restrict__ z,
                                                  float* __restrict__ zsum) {
    const int c    = blockIdx.x;     // channel
    const int lane = threadIdx.x;    // 0..63

    const f32x4* zp = reinterpret_cast<const f32x4*>(z + (size_t)c * P);
    float s = 0.f;
#pragma unroll
    for (int i = 0; i < 4; ++i) {    // 4 * 64 lanes * 4 floats = 1024 = P
        f32x4 v = __builtin_nontemporal_load(&zp[i * 64 + lane]);
        s += (v.x + v.y) + (v.z + v.w);
    }
#pragma unroll
    for (int off = 32; off > 0; off >>= 1)
        s += __shfl_down(s, off, 64);
    if (lane == 0) zsum[c] = s;
}

// ---------------------------------------------------------------------------
// Kernel 2: out[pix4] = 0.001 * sum_c zs[c] * x4[c][pix4]
// 768 single-wave blocks (3/CU even), each thread owns one float4 (4 pixels)
// across all 512 channels -> 1 KB contiguous per wave per channel step,
// single plain float4 store, no partials/atomics/combine.
// unroll 32: 32 outstanding dwordx4 loads per wave to smooth VMEM issue.
// x read-once + out write-once -> non-temporal.
// ---------------------------------------------------------------------------
__global__ __launch_bounds__(64) void corr_kernel(const float* __restrict__ x,
                                                  const float* __restrict__ zsum,
                                                  f32x4* __restrict__ out) {
    __shared__ float zs[C];
#pragma unroll
    for (int i = 0; i < C / 64; ++i)
        zs[i * 64 + threadIdx.x] = zsum[i * 64 + threadIdx.x];
    __syncthreads();

    const int gid = blockIdx.x * 64 + threadIdx.x;  // [0, NF4)
    const int b   = gid >> 14;                      // / (NPIX/4 = 16384)
    const int n4  = gid & 16383;

    const f32x4* xp = reinterpret_cast<const f32x4*>(x)
                    + (size_t)b * (C * (NPIX / 4))
                    + n4;

    float ax = 0.f, ay = 0.f, az = 0.f, aw = 0.f;
#pragma unroll 32
    for (int c = 0; c < C; ++c) {
        const f32x4 v = __builtin_nontemporal_load(&xp[(size_t)c * (NPIX / 4)]);
        const float s = zs[c];
        ax += s * v.x; ay += s * v.y; az += s * v.z; aw += s * v.w;
    }

    f32x4 r; r.x = ax * 0.001f; r.y = ay * 0.001f; r.z = az * 0.001f; r.w = aw * 0.001f;
    __builtin_nontemporal_store(r, &out[gid]);
}

extern "C" void kernel_launch(void* const* d_in, const int* in_sizes, int n_in,
                              void* d_out, int out_size, void* d_ws, size_t ws_size,
                              hipStream_t stream) {
    const float* z    = (const float*)d_in[0];  // (1,512,32,32)
    const float* x    = (const float*)d_in[1];  // (3,512,256,256)
    float*       zsum = (float*)d_ws;           // 512 floats of scratch

    // Kernel 1: one wave per channel, 512 blocks (2/CU).
    zsum_kernel<<<dim3(C), 64, 0, stream>>>(z, zsum);

    // Kernel 2: 768 single-wave blocks (3/CU), one float4 per thread.
    corr_kernel<<<dim3(NF4 / 64), 64, 0, stream>>>(x, zsum, (f32x4*)d_out);
}

// Round 7
// 67.140 us; speedup vs baseline: 1.4893x; 1.4893x over previous
//
#include <hip/hip_runtime.h>

// Problem constants (fixed by the reference):
//   z: (1, 512, 32, 32) fp32   -> C=512 channels, P=1024 template positions
//   x: (3, 512, 256, 256) fp32 -> B=3, N=65536 pixels
// res[b,n] = 0.001 * sum_c ( sum_p z[c,p] ) * x[b,c,n]
constexpr int C    = 512;
constexpr int P    = 1024;     // 32*32
constexpr int NPIX = 65536;    // 256*256
constexpr int B    = 3;
constexpr int NF4  = B * NPIX / 4;    // 49152 float4 outputs

// Native clang vector type: __builtin_nontemporal_load accepts this
// (HIP_vector_type float4 is a struct -> rejected).
typedef float f32x4 __attribute__((ext_vector_type(4)));

// ---------------------------------------------------------------------------
// Kernel 1: zsum[c] = sum over P of z[c,p]. One single-wave block per channel
// (512 blocks = 2/CU even spread). Lane l reads 4 float4s -> coalesced 1 KB
// per wave per step.
// ---------------------------------------------------------------------------
__global__ __launch_bounds__(64) void zsum_kernel(const float* __restrict__ z,
                                                  float* __restrict__ zsum) {
    const int c    = blockIdx.x;     // channel
    const int lane = threadIdx.x;    // 0..63

    const f32x4* zp = reinterpret_cast<const f32x4*>(z + (size_t)c * P);
    float s = 0.f;
#pragma unroll
    for (int i = 0; i < 4; ++i) {    // 4 * 64 lanes * 4 floats = 1024 = P
        f32x4 v = zp[i * 64 + lane];
        s += (v.x + v.y) + (v.z + v.w);
    }
#pragma unroll
    for (int off = 32; off > 0; off >>= 1)
        s += __shfl_down(s, off, 64);
    if (lane == 0) zsum[c] = s;
}

// ---------------------------------------------------------------------------
// Kernel 2: out[pix4] = 0.001 * sum_c zs[c] * x4[c][pix4]
// 768 single-wave blocks (3/CU even), each thread owns one float4 (4 pixels)
// across all 512 channels -> 1 KB contiguous per wave per channel step,
// single plain float4 store, no partials/atomics/combine.
// unroll 16 is the compiler's sweet spot (unroll 32 regressed 68->100 us:
// too many in-flight dwordx4 destinations -> VGPR pressure serializes issue).
// x is read-once (384 MB): non-temporal loads skip L2 fill.
// ---------------------------------------------------------------------------
__global__ __launch_bounds__(64) void corr_kernel(const float* __restrict__ x,
                                                  const float* __restrict__ zsum,
                                                  f32x4* __restrict__ out) {
    __shared__ float zs[C];
#pragma unroll
    for (int i = 0; i < C / 64; ++i)
        zs[i * 64 + threadIdx.x] = zsum[i * 64 + threadIdx.x];
    __syncthreads();

    const int gid = blockIdx.x * 64 + threadIdx.x;  // [0, NF4)
    const int b   = gid >> 14;                      // / (NPIX/4 = 16384)
    const int n4  = gid & 16383;

    const f32x4* xp = reinterpret_cast<const f32x4*>(x)
                    + (size_t)b * (C * (NPIX / 4))
                    + n4;

    float ax = 0.f, ay = 0.f, az = 0.f, aw = 0.f;
#pragma unroll 16
    for (int c = 0; c < C; ++c) {
        const f32x4 v = __builtin_nontemporal_load(&xp[(size_t)c * (NPIX / 4)]);
        const float s = zs[c];
        ax += s * v.x; ay += s * v.y; az += s * v.z; aw += s * v.w;
    }

    f32x4 r; r.x = ax * 0.001f; r.y = ay * 0.001f; r.z = az * 0.001f; r.w = aw * 0.001f;
    out[gid] = r;
}

extern "C" void kernel_launch(void* const* d_in, const int* in_sizes, int n_in,
                              void* d_out, int out_size, void* d_ws, size_t ws_size,
                              hipStream_t stream) {
    const float* z    = (const float*)d_in[0];  // (1,512,32,32)
    const float* x    = (const float*)d_in[1];  // (3,512,256,256)
    float*       zsum = (float*)d_ws;           // 512 floats of scratch

    // Kernel 1: one wave per channel, 512 blocks (2/CU).
    zsum_kernel<<<dim3(C), 64, 0, stream>>>(z, zsum);

    // Kernel 2: 768 single-wave blocks (3/CU), one float4 per thread.
    corr_kernel<<<dim3(NF4 / 64), 64, 0, stream>>>(x, zsum, (f32x4*)d_out);
}